// Round 1
// 591.331 us; speedup vs baseline: 1.0257x; 1.0257x over previous
//
#include <hip/hip_runtime.h>

#define USER_NUM 100000
#define ITEM_NUM 50000
#define N_NODES  150000   // USER_NUM + ITEM_NUM
#define EMB_DIM  64
#define NNZ      4800000

#define CB_SHIFT 10
#define ROWS_PER_CB 1024
#define NCB ((N_NODES + ROWS_PER_CB - 1) / ROWS_PER_CB)   // 147
#define CB_CAP 34000            // expected 32.7k edges/bucket, ~7 sigma slack
#define TILE 8192
#define NTILES ((NNZ + TILE - 1) / TILE)  // 586
#define EPT 32                  // edges per thread in partition

// bf16 helpers: unpack a uint32 holding two bf16 (low ushort = even elem)
__device__ __forceinline__ float bflo(unsigned u) {
    return __uint_as_float(u << 16);
}
__device__ __forceinline__ float bfhi(unsigned u) {
    return __uint_as_float(u & 0xFFFF0000u);
}
// fp32 -> bf16 (RNE), returned in low 16 bits
__device__ __forceinline__ unsigned f2bf(float f) {
    unsigned u = __float_as_uint(f);
    return (u + 0x7FFFu + ((u >> 16) & 1u)) >> 16;
}

// ---------------------------------------------------------------------------
// init: acc (= d_out) = concat(user_emb, item_emb) fp32;
//       xb = same, packed bf16 (8 elems = uint4 per thread)
// ---------------------------------------------------------------------------
__global__ void lgcn_init(const float4* __restrict__ user,
                          const float4* __restrict__ item,
                          uint4* __restrict__ xb,
                          float4* __restrict__ acc) {
    int i = blockIdx.x * blockDim.x + threadIdx.x;   // chunk of 8 floats
    if (i >= N_NODES * 8) return;
    const int user_chunks = USER_NUM * 8;
    float4 f0, f1;
    if (i < user_chunks) {
        f0 = user[i * 2];
        f1 = user[i * 2 + 1];
    } else {
        f0 = item[(i - user_chunks) * 2];
        f1 = item[(i - user_chunks) * 2 + 1];
    }
    acc[i * 2]     = f0;
    acc[i * 2 + 1] = f1;
    uint4 p;
    p.x = f2bf(f0.x) | (f2bf(f0.y) << 16);
    p.y = f2bf(f0.z) | (f2bf(f0.w) << 16);
    p.z = f2bf(f1.x) | (f2bf(f1.y) << 16);
    p.w = f2bf(f1.z) | (f2bf(f1.w) << 16);
    xb[i] = p;
}

// ---------------------------------------------------------------------------
// bucket cursor init: bucket b's staging region starts at b*CB_CAP
// ---------------------------------------------------------------------------
__global__ void lgcn_bcur_init(int* __restrict__ bucket_cursor) {
    int b = blockIdx.x * blockDim.x + threadIdx.x;
    if (b < NCB) bucket_cursor[b] = b * CB_CAP;
}

// ---------------------------------------------------------------------------
// partition: per 8192-edge tile, in-LDS counting sort by coarse bucket
// (1024 rows each), then write staging in sorted slot order (consecutive
// threads -> consecutive addresses). Staging entry packs
// (rlo<<18 | col, val) -> one 8B word/edge. NO global atomics except 147
// run reservations per block.                       (unchanged from R9)
// ---------------------------------------------------------------------------
__global__ __launch_bounds__(256) void lgcn_partition(
    const int* __restrict__ row,
    const int* __restrict__ col,
    const float* __restrict__ vals,
    int* __restrict__ bucket_cursor,  // pre-init to b*CB_CAP
    int2* __restrict__ t_cv) {
    __shared__ int hist[NCB];
    __shared__ int excl[NCB];        // exclusive start, then running cursor
    __shared__ int delta[NCB];       // global pos = delta[b] + slot
    __shared__ unsigned lslot[TILE];
    __shared__ int sscan[256];

    int tid = threadIdx.x;
    int tileStart = blockIdx.x * TILE;
    int tileCount = NNZ - tileStart;
    if (tileCount > TILE) tileCount = TILE;

    for (int b = tid; b < NCB; b += 256) hist[b] = 0;
    __syncthreads();

    // phase A: LDS bucket histogram; cache rows in regs
    int rws[EPT];
#pragma unroll
    for (int k = 0; k < EPT; ++k) {
        int le = tid + k * 256;
        int r = -1;
        if (le < tileCount) {
            r = row[tileStart + le];
            atomicAdd(&hist[r >> CB_SHIFT], 1);
        }
        rws[k] = r;
    }
    __syncthreads();

    // phase B: exclusive scan of hist (NCB=147 <= 256: one bucket per thread),
    // then reserve the global run and compute delta in the same thread.
    int h = (tid < NCB) ? hist[tid] : 0;
    sscan[tid] = h;
    __syncthreads();
    for (int off = 1; off < 256; off <<= 1) {
        int x = (tid >= off) ? sscan[tid - off] : 0;
        __syncthreads();
        sscan[tid] += x;
        __syncthreads();
    }
    if (tid < NCB) {
        int ex = sscan[tid] - h;
        excl[tid] = ex;
        int rb = h ? atomicAdd(&bucket_cursor[tid], h) : 0;
        delta[tid] = rb - ex;
    }
    __syncthreads();

    // phase C: place edges into bucket-sorted local slots
    // pack: bucket (<147) << 23 | rlo (<1024) << 13 | le (<8192)
#pragma unroll
    for (int k = 0; k < EPT; ++k) {
        int le = tid + k * 256;
        if (le < tileCount) {
            int r = rws[k];
            int b = r >> CB_SHIFT;
            int lp = atomicAdd(&excl[b], 1);
            lslot[lp] = ((unsigned)b << 23) |
                        ((unsigned)(r & (ROWS_PER_CB - 1)) << 13) |
                        (unsigned)le;
        }
    }
    __syncthreads();

    // phase D: write out in slot order -> coalesced per-run bursts
    for (int i = tid; i < tileCount; i += 256) {
        unsigned s = lslot[i];
        int b = s >> 23;
        int rlo = (s >> 13) & (ROWS_PER_CB - 1);
        int le = s & 8191;
        int e = tileStart + le;
        int gpos = delta[b] + i;
        if (gpos < (b + 1) * CB_CAP) {   // overflow guard, statistically never
            t_cv[gpos] = make_int2((rlo << 18) | col[e],
                                   __float_as_int(vals[e]));
        }
    }
}

// ---------------------------------------------------------------------------
// finalize: one block per coarse bucket. Replaces count + 3 scan kernels +
// scatter. The block's ~265KB staging segment is read once from HBM
// (histogram pass), stays L2-resident, and is re-read for the scatter pass.
// Dense CSR base is derived from a 147-element scan of bucket_cursor
// (no global row_ptr scan). Emits per-row int2{start,end}.
// ---------------------------------------------------------------------------
__global__ __launch_bounds__(256) void lgcn_finalize(
    const int* __restrict__ bucket_cursor,
    const int2* __restrict__ t_cv,
    int2* __restrict__ csr_cv,
    int2* __restrict__ row_se) {
    __shared__ int hist[ROWS_PER_CB];
    __shared__ int cur[ROWS_PER_CB];
    __shared__ int sscan[256];
    int t = threadIdx.x;
    int b = blockIdx.x;

    // scan clamped per-bucket counts -> dense csr base + own count
    int v = 0;
    if (t < NCB) {
        int cb = bucket_cursor[t] - t * CB_CAP;
        v = (cb > CB_CAP) ? CB_CAP : cb;
    }
    sscan[t] = v;
    __syncthreads();
    for (int off = 1; off < 256; off <<= 1) {
        int x = (t >= off) ? sscan[t - off] : 0;
        __syncthreads();
        sscan[t] += x;
        __syncthreads();
    }
    int prev = (b == 0) ? 0 : sscan[b - 1];
    int bbase = prev;                 // dense CSR base of this bucket
    int count = sscan[b] - prev;      // clamped edge count of this bucket

    int lo = b * ROWS_PER_CB;
    int nrows = N_NODES - lo;
    if (nrows > ROWS_PER_CB) nrows = ROWS_PER_CB;

    for (int i = t; i < ROWS_PER_CB; i += 256) hist[i] = 0;
    __syncthreads();

    // pass 1: per-row histogram (segment read from HBM -> lands in L2)
    int base = b * CB_CAP;
    for (int e = base + t; e < base + count; e += 256)
        atomicAdd(&hist[(unsigned)t_cv[e].x >> 18], 1);
    __syncthreads();

    // scan hist[1024]: thread t owns elements 4t..4t+3
    int4 hh = ((const int4*)hist)[t];
    int tsum = hh.x + hh.y + hh.z + hh.w;
    sscan[t] = tsum;
    __syncthreads();
    for (int off = 1; off < 256; off <<= 1) {
        int x = (t >= off) ? sscan[t - off] : 0;
        __syncthreads();
        sscan[t] += x;
        __syncthreads();
    }
    int p = bbase + sscan[t] - tsum;  // exclusive prefix within bucket
    int hv[4] = {hh.x, hh.y, hh.z, hh.w};
    int i0 = t * 4;
#pragma unroll
    for (int k = 0; k < 4; ++k) {
        if (i0 + k < nrows) {
            row_se[lo + i0 + k] = make_int2(p, p + hv[k]);
            cur[i0 + k] = p;
        }
        p += hv[k];
    }
    __syncthreads();

    // pass 2: scatter into dense CSR (segment re-read hits L2)
    for (int e = base + t; e < base + count; e += 256) {
        int2 cv = t_cv[e];
        int rlo = (unsigned)cv.x >> 18;
        int pos = atomicAdd(&cur[rlo], 1);
        csr_cv[pos] = make_int2(cv.x & 0x3FFFF, cv.y);
    }
}

// ---------------------------------------------------------------------------
// SpMM, bf16 gather: one wave per row. Lanes = 8 edge-subgroups x 8 chunks.
// Each lane loads 16B = 8 bf16 of x[col]; a row is 128B = ONE cache line.
// 4-edge superstep per subgroup: 4 independent csr loads then 4 independent
// gathers in flight (2x the MLP of the old 2-edge loop -> hides the
// ~600-900cy L2-miss gather latency). Single accumulator set (FMA chains are
// 8 instrs apart, no latency stall) keeps VGPR under the 64-reg/8-wave point.
// ---------------------------------------------------------------------------
#define FMA8(vv, uu) do {                                          \
    a[0] += (vv) * bflo((uu).x); a[1] += (vv) * bfhi((uu).x);      \
    a[2] += (vv) * bflo((uu).y); a[3] += (vv) * bfhi((uu).y);      \
    a[4] += (vv) * bflo((uu).z); a[5] += (vv) * bfhi((uu).z);      \
    a[6] += (vv) * bflo((uu).w); a[7] += (vv) * bfhi((uu).w);      \
} while (0)

__global__ __launch_bounds__(256, 8) void lgcn_spmm_bf16(
    const int2* __restrict__ row_se,
    const int2* __restrict__ csr_cv,
    const uint4* __restrict__ xb,
    uint4* __restrict__ yb,
    float4* __restrict__ acc,
    float scale) {
    int gid = blockIdx.x * blockDim.x + threadIdx.x;
    int r = gid >> 6;
    if (r >= N_NODES) return;
    int lane = threadIdx.x & 63;
    int c = lane & 7;        // which 16B chunk (8 bf16) of the 64-dim row
    int sub = lane >> 3;     // edge subgroup 0..7

    int2 se = row_se[r];
    int start = se.x;
    int end = se.y;

    float a[8] = {0.f, 0.f, 0.f, 0.f, 0.f, 0.f, 0.f, 0.f};

    int e = start + sub;
    // main loop: 32 edges per wave iteration (4 per subgroup, independent)
    for (; e + 24 < end; e += 32) {
        int2 cv0 = csr_cv[e];
        int2 cv1 = csr_cv[e + 8];
        int2 cv2 = csr_cv[e + 16];
        int2 cv3 = csr_cv[e + 24];
        uint4 u0 = xb[cv0.x * 8 + c];
        uint4 u1 = xb[cv1.x * 8 + c];
        uint4 u2 = xb[cv2.x * 8 + c];
        uint4 u3 = xb[cv3.x * 8 + c];
        float v0 = __int_as_float(cv0.y);
        float v1 = __int_as_float(cv1.y);
        float v2 = __int_as_float(cv2.y);
        float v3 = __int_as_float(cv3.y);
        FMA8(v0, u0);
        FMA8(v1, u1);
        FMA8(v2, u2);
        FMA8(v3, u3);
    }
    // tail: at most 3 edges left per subgroup -> one pair step + one single
    if (e + 8 < end) {
        int2 cv0 = csr_cv[e];
        int2 cv1 = csr_cv[e + 8];
        uint4 u0 = xb[cv0.x * 8 + c];
        uint4 u1 = xb[cv1.x * 8 + c];
        float v0 = __int_as_float(cv0.y);
        float v1 = __int_as_float(cv1.y);
        FMA8(v0, u0);
        FMA8(v1, u1);
        e += 16;
    }
    if (e < end) {
        int2 cv = csr_cv[e];
        uint4 u = xb[cv.x * 8 + c];
        float v = __int_as_float(cv.y);
        FMA8(v, u);
    }

    // reduce across the 8 edge subgroups (lanes differing in bits 3,4,5)
#pragma unroll
    for (int k = 0; k < 8; ++k) {
        a[k] += __shfl_xor(a[k], 8);
        a[k] += __shfl_xor(a[k], 16);
        a[k] += __shfl_xor(a[k], 32);
    }

    if (sub == 0) {
        // bf16 y for the next layer's gather
        uint4 p;
        p.x = f2bf(a[0]) | (f2bf(a[1]) << 16);
        p.y = f2bf(a[2]) | (f2bf(a[3]) << 16);
        p.z = f2bf(a[4]) | (f2bf(a[5]) << 16);
        p.w = f2bf(a[6]) | (f2bf(a[7]) << 16);
        yb[r * 8 + c] = p;
        // fp32 accumulator update (full-precision y folded in)
        int idx = r * 16 + c * 2;
        float4 o0 = acc[idx];
        float4 o1 = acc[idx + 1];
        o0.x = (o0.x + a[0]) * scale;
        o0.y = (o0.y + a[1]) * scale;
        o0.z = (o0.z + a[2]) * scale;
        o0.w = (o0.w + a[3]) * scale;
        o1.x = (o1.x + a[4]) * scale;
        o1.y = (o1.y + a[5]) * scale;
        o1.z = (o1.z + a[6]) * scale;
        o1.w = (o1.w + a[7]) * scale;
        acc[idx] = o0;
        acc[idx + 1] = o1;
    }
}

extern "C" void kernel_launch(void* const* d_in, const int* in_sizes, int n_in,
                              void* d_out, int out_size, void* d_ws, size_t ws_size,
                              hipStream_t stream) {
    const float* user_emb = (const float*)d_in[0];
    const float* item_emb = (const float*)d_in[1];
    const int*   adj_row  = (const int*)d_in[2];
    const int*   adj_col  = (const int*)d_in[3];
    const float* adj_vals = (const float*)d_in[4];
    float* out = (float*)d_out;

    // workspace layout (~98.8 MB, unchanged):
    //   xb_a (19.2MB) | csr_cv (38.4MB) | S (union): t_cv staging (40MB)
    //   during CSR build, xb_b (19.2MB) during layers | row_se | cursor
    char* base = (char*)d_ws;
    uint4* xb_a   = (uint4*)base;                               // 19.2 MB
    int2*  csr_cv = (int2*)(base + 19200000);                   // 38.4 MB
    char*  S      = base + 57600000;
    const size_t T_ENTRIES = (size_t)NCB * CB_CAP;              // 4,998,000
    int2*  t_cv   = (int2*)S;                                   // 40.0 MB
    uint4* xb_b   = (uint4*)S;                                  // aliases t_cv
    char*  tail   = S + T_ENTRIES * 8;
    int2*  row_se = (int2*)tail;                                // 1.2 MB
    int*   bucket_cursor = (int*)(tail + (size_t)N_NODES * 8);  // 147 ints

    // init: xb_a = bf16(concat(user,item)); out (acc) = fp32 concat
    {
        int threads = 256;
        int blocks = (N_NODES * 8 + threads - 1) / threads;
        lgcn_init<<<blocks, threads, 0, stream>>>(
            (const float4*)user_emb, (const float4*)item_emb,
            xb_a, (float4*)out);
    }

    // ---- CSR build: partition -> single fused finalize ----
    lgcn_bcur_init<<<1, 256, 0, stream>>>(bucket_cursor);
    lgcn_partition<<<NTILES, 256, 0, stream>>>(
        adj_row, adj_col, adj_vals, bucket_cursor, t_cv);
    lgcn_finalize<<<NCB, 256, 0, stream>>>(
        bucket_cursor, t_cv, csr_cv, row_se);

    // ---- 3 propagation layers (bf16-gather SpMM, fused fp32 acc update) ----
    const int spmm_block = 256;                       // 4 waves = 4 rows / block
    const int spmm_grid = (N_NODES * 64 + spmm_block - 1) / spmm_block;
    uint4* xa = xb_a;
    uint4* xbv = xb_b;
    for (int layer = 0; layer < 3; ++layer) {
        float scale = (layer == 2) ? 0.25f : 1.0f;
        lgcn_spmm_bf16<<<spmm_grid, spmm_block, 0, stream>>>(
            row_se, csr_cv, xa, xbv, (float4*)out, scale);
        uint4* t = xa; xa = xbv; xbv = t;
    }
}

// Round 2
// 524.656 us; speedup vs baseline: 1.1561x; 1.1271x over previous
//
#include <hip/hip_runtime.h>

#define USER_NUM 100000
#define ITEM_NUM 50000
#define N_NODES  150000   // USER_NUM + ITEM_NUM
#define EMB_DIM  64
#define NNZ      4800000

#define CB_SHIFT 10
#define ROWS_PER_CB 1024
#define NCB ((N_NODES + ROWS_PER_CB - 1) / ROWS_PER_CB)   // 147
#define CB_CAP 34000            // expected 32.7k edges/bucket, ~7 sigma slack
#define TILE 8192
#define NTILES ((NNZ + TILE - 1) / TILE)  // 586
#define EPT 32                  // edges per thread in partition

// bf16 helpers: unpack a uint32 holding two bf16 (low ushort = even elem)
__device__ __forceinline__ float bflo(unsigned u) {
    return __uint_as_float(u << 16);
}
__device__ __forceinline__ float bfhi(unsigned u) {
    return __uint_as_float(u & 0xFFFF0000u);
}
// fp32 -> bf16 (RNE), returned in low 16 bits
__device__ __forceinline__ unsigned f2bf(float f) {
    unsigned u = __float_as_uint(f);
    return (u + 0x7FFFu + ((u >> 16) & 1u)) >> 16;
}

// ---------------------------------------------------------------------------
// init: xb = bf16(concat(user_emb, item_emb)), packed 8 elems = uint4/thread.
// (acc stream removed: final output is formed in the layer-3 SpMM epilogue)
// ---------------------------------------------------------------------------
__global__ void lgcn_init(const float4* __restrict__ user,
                          const float4* __restrict__ item,
                          uint4* __restrict__ xb) {
    int i = blockIdx.x * blockDim.x + threadIdx.x;   // chunk of 8 floats
    if (i >= N_NODES * 8) return;
    const int user_chunks = USER_NUM * 8;
    float4 f0, f1;
    if (i < user_chunks) {
        f0 = user[i * 2];
        f1 = user[i * 2 + 1];
    } else {
        f0 = item[(i - user_chunks) * 2];
        f1 = item[(i - user_chunks) * 2 + 1];
    }
    uint4 p;
    p.x = f2bf(f0.x) | (f2bf(f0.y) << 16);
    p.y = f2bf(f0.z) | (f2bf(f0.w) << 16);
    p.z = f2bf(f1.x) | (f2bf(f1.y) << 16);
    p.w = f2bf(f1.z) | (f2bf(f1.w) << 16);
    xb[i] = p;
}

// ---------------------------------------------------------------------------
// bucket cursor init: bucket b's staging region starts at b*CB_CAP
// ---------------------------------------------------------------------------
__global__ void lgcn_bcur_init(int* __restrict__ bucket_cursor) {
    int b = blockIdx.x * blockDim.x + threadIdx.x;
    if (b < NCB) bucket_cursor[b] = b * CB_CAP;
}

// ---------------------------------------------------------------------------
// partition: per 8192-edge tile, in-LDS counting sort by coarse bucket
// (1024 rows each), then write staging in sorted slot order (consecutive
// threads -> consecutive addresses). Staging entry packs
// (rlo<<18 | col, val) -> one 8B word/edge. NO global atomics except 147
// run reservations per block.                               (unchanged)
// ---------------------------------------------------------------------------
__global__ __launch_bounds__(256) void lgcn_partition(
    const int* __restrict__ row,
    const int* __restrict__ col,
    const float* __restrict__ vals,
    int* __restrict__ bucket_cursor,  // pre-init to b*CB_CAP
    int2* __restrict__ t_cv) {
    __shared__ int hist[NCB];
    __shared__ int excl[NCB];        // exclusive start, then running cursor
    __shared__ int delta[NCB];       // global pos = delta[b] + slot
    __shared__ unsigned lslot[TILE];
    __shared__ int sscan[256];

    int tid = threadIdx.x;
    int tileStart = blockIdx.x * TILE;
    int tileCount = NNZ - tileStart;
    if (tileCount > TILE) tileCount = TILE;

    for (int b = tid; b < NCB; b += 256) hist[b] = 0;
    __syncthreads();

    // phase A: LDS bucket histogram; cache rows in regs
    int rws[EPT];
#pragma unroll
    for (int k = 0; k < EPT; ++k) {
        int le = tid + k * 256;
        int r = -1;
        if (le < tileCount) {
            r = row[tileStart + le];
            atomicAdd(&hist[r >> CB_SHIFT], 1);
        }
        rws[k] = r;
    }
    __syncthreads();

    // phase B: exclusive scan of hist (NCB=147 <= 256: one bucket per thread),
    // then reserve the global run and compute delta in the same thread.
    int h = (tid < NCB) ? hist[tid] : 0;
    sscan[tid] = h;
    __syncthreads();
    for (int off = 1; off < 256; off <<= 1) {
        int x = (tid >= off) ? sscan[tid - off] : 0;
        __syncthreads();
        sscan[tid] += x;
        __syncthreads();
    }
    if (tid < NCB) {
        int ex = sscan[tid] - h;
        excl[tid] = ex;
        int rb = h ? atomicAdd(&bucket_cursor[tid], h) : 0;
        delta[tid] = rb - ex;
    }
    __syncthreads();

    // phase C: place edges into bucket-sorted local slots
    // pack: bucket (<147) << 23 | rlo (<1024) << 13 | le (<8192)
#pragma unroll
    for (int k = 0; k < EPT; ++k) {
        int le = tid + k * 256;
        if (le < tileCount) {
            int r = rws[k];
            int b = r >> CB_SHIFT;
            int lp = atomicAdd(&excl[b], 1);
            lslot[lp] = ((unsigned)b << 23) |
                        ((unsigned)(r & (ROWS_PER_CB - 1)) << 13) |
                        (unsigned)le;
        }
    }
    __syncthreads();

    // phase D: write out in slot order -> coalesced per-run bursts
    for (int i = tid; i < tileCount; i += 256) {
        unsigned s = lslot[i];
        int b = s >> 23;
        int rlo = (s >> 13) & (ROWS_PER_CB - 1);
        int le = s & 8191;
        int e = tileStart + le;
        int gpos = delta[b] + i;
        if (gpos < (b + 1) * CB_CAP) {   // overflow guard, statistically never
            t_cv[gpos] = make_int2((rlo << 18) | col[e],
                                   __float_as_int(vals[e]));
        }
    }
}

// ---------------------------------------------------------------------------
// finalize: one 1024-thread block per coarse bucket (was 256: 5.8% occupancy,
// pure latency). 16 waves/block + 4-deep load batching in both passes.
// Pass 1 histograms the bucket's staging segment (lands in L2), in-LDS scan
// emits per-row int2{start,end}; pass 2 scatters to dense CSR (L2 re-read).
// ---------------------------------------------------------------------------
__global__ __launch_bounds__(1024) void lgcn_finalize(
    const int* __restrict__ bucket_cursor,
    const int2* __restrict__ t_cv,
    int2* __restrict__ csr_cv,
    int2* __restrict__ row_se) {
    __shared__ int hist[ROWS_PER_CB];
    __shared__ int cur[ROWS_PER_CB];
    __shared__ int sscan[1024];
    int t = threadIdx.x;
    int b = blockIdx.x;

    // scan clamped per-bucket counts -> dense csr base + own count
    int v = 0;
    if (t < NCB) {
        int cb = bucket_cursor[t] - t * CB_CAP;
        v = (cb > CB_CAP) ? CB_CAP : cb;
    }
    if (t < 256) sscan[t] = v;
    __syncthreads();
    for (int off = 1; off < 256; off <<= 1) {
        int x = 0;
        if (t < 256 && t >= off) x = sscan[t - off];
        __syncthreads();
        if (t < 256) sscan[t] += x;
        __syncthreads();
    }
    int prev = (b == 0) ? 0 : sscan[b - 1];
    int bbase = prev;                 // dense CSR base of this bucket
    int count = sscan[b] - prev;      // clamped edge count of this bucket
    __syncthreads();

    int lo = b * ROWS_PER_CB;
    int nrows = N_NODES - lo;
    if (nrows > ROWS_PER_CB) nrows = ROWS_PER_CB;

    hist[t] = 0;
    __syncthreads();

    // pass 1: per-row histogram, 4 loads in flight per thread
    int base = b * CB_CAP;
    int eEnd = base + count;
    int e = base + t;
    for (; e + 3 * 1024 < eEnd; e += 4 * 1024) {
        int2 c0 = t_cv[e];
        int2 c1 = t_cv[e + 1024];
        int2 c2 = t_cv[e + 2048];
        int2 c3 = t_cv[e + 3072];
        atomicAdd(&hist[(unsigned)c0.x >> 18], 1);
        atomicAdd(&hist[(unsigned)c1.x >> 18], 1);
        atomicAdd(&hist[(unsigned)c2.x >> 18], 1);
        atomicAdd(&hist[(unsigned)c3.x >> 18], 1);
    }
    for (; e < eEnd; e += 1024)
        atomicAdd(&hist[(unsigned)t_cv[e].x >> 18], 1);
    __syncthreads();

    // scan hist[1024], one element per thread
    int h = hist[t];
    sscan[t] = h;
    __syncthreads();
    for (int off = 1; off < 1024; off <<= 1) {
        int x = (t >= off) ? sscan[t - off] : 0;
        __syncthreads();
        sscan[t] += x;
        __syncthreads();
    }
    int p = bbase + sscan[t] - h;     // exclusive prefix within bucket
    if (t < nrows) {
        row_se[lo + t] = make_int2(p, p + h);
        cur[t] = p;
    }
    __syncthreads();

    // pass 2: scatter into dense CSR (segment re-read hits L2)
    e = base + t;
    for (; e + 3 * 1024 < eEnd; e += 4 * 1024) {
        int2 c0 = t_cv[e];
        int2 c1 = t_cv[e + 1024];
        int2 c2 = t_cv[e + 2048];
        int2 c3 = t_cv[e + 3072];
        int p0 = atomicAdd(&cur[(unsigned)c0.x >> 18], 1);
        int p1 = atomicAdd(&cur[(unsigned)c1.x >> 18], 1);
        int p2 = atomicAdd(&cur[(unsigned)c2.x >> 18], 1);
        int p3 = atomicAdd(&cur[(unsigned)c3.x >> 18], 1);
        csr_cv[p0] = make_int2(c0.x & 0x3FFFF, c0.y);
        csr_cv[p1] = make_int2(c1.x & 0x3FFFF, c1.y);
        csr_cv[p2] = make_int2(c2.x & 0x3FFFF, c2.y);
        csr_cv[p3] = make_int2(c3.x & 0x3FFFF, c3.y);
    }
    for (; e < eEnd; e += 1024) {
        int2 cv = t_cv[e];
        int pos = atomicAdd(&cur[(unsigned)cv.x >> 18], 1);
        csr_cv[pos] = make_int2(cv.x & 0x3FFFF, cv.y);
    }
}

// ---------------------------------------------------------------------------
// SpMM, bf16 gather: one wave per row. Lanes = 8 edge-subgroups x 8 chunks.
// Each lane loads 16B = 8 bf16 of x[col]; a row is 128B = ONE cache line.
// Layers 1-2: write bf16 y only (no acc stream -> -76.8MB HBM per layer).
// ---------------------------------------------------------------------------
#define FMA8(vv, uu) do {                                          \
    a[0] += (vv) * bflo((uu).x); a[1] += (vv) * bfhi((uu).x);      \
    a[2] += (vv) * bflo((uu).y); a[3] += (vv) * bfhi((uu).y);      \
    a[4] += (vv) * bflo((uu).z); a[5] += (vv) * bfhi((uu).z);      \
    a[6] += (vv) * bflo((uu).w); a[7] += (vv) * bfhi((uu).w);      \
} while (0)

#define SPMM_BODY                                                  \
    int gid = blockIdx.x * blockDim.x + threadIdx.x;               \
    int r = gid >> 6;                                              \
    if (r >= N_NODES) return;                                      \
    int lane = threadIdx.x & 63;                                   \
    int c = lane & 7;                                              \
    int sub = lane >> 3;                                           \
    int2 se = row_se[r];                                           \
    int start = se.x;                                              \
    int end = se.y;                                                \
    float a[8] = {0.f, 0.f, 0.f, 0.f, 0.f, 0.f, 0.f, 0.f};         \
    int e = start + sub;                                           \
    for (; e + 24 < end; e += 32) {                                \
        int2 cv0 = csr_cv[e];                                      \
        int2 cv1 = csr_cv[e + 8];                                  \
        int2 cv2 = csr_cv[e + 16];                                 \
        int2 cv3 = csr_cv[e + 24];                                 \
        uint4 u0 = xb[cv0.x * 8 + c];                              \
        uint4 u1 = xb[cv1.x * 8 + c];                              \
        uint4 u2 = xb[cv2.x * 8 + c];                              \
        uint4 u3 = xb[cv3.x * 8 + c];                              \
        float v0 = __int_as_float(cv0.y);                          \
        float v1 = __int_as_float(cv1.y);                          \
        float v2 = __int_as_float(cv2.y);                          \
        float v3 = __int_as_float(cv3.y);                          \
        FMA8(v0, u0);                                              \
        FMA8(v1, u1);                                              \
        FMA8(v2, u2);                                              \
        FMA8(v3, u3);                                              \
    }                                                              \
    if (e + 8 < end) {                                             \
        int2 cv0 = csr_cv[e];                                      \
        int2 cv1 = csr_cv[e + 8];                                  \
        uint4 u0 = xb[cv0.x * 8 + c];                              \
        uint4 u1 = xb[cv1.x * 8 + c];                              \
        float v0 = __int_as_float(cv0.y);                          \
        float v1 = __int_as_float(cv1.y);                          \
        FMA8(v0, u0);                                              \
        FMA8(v1, u1);                                              \
        e += 16;                                                   \
    }                                                              \
    if (e < end) {                                                 \
        int2 cv = csr_cv[e];                                       \
        uint4 u = xb[cv.x * 8 + c];                                \
        float v = __int_as_float(cv.y);                            \
        FMA8(v, u);                                                \
    }                                                              \
    _Pragma("unroll")                                              \
    for (int k = 0; k < 8; ++k) {                                  \
        a[k] += __shfl_xor(a[k], 8);                               \
        a[k] += __shfl_xor(a[k], 16);                              \
        a[k] += __shfl_xor(a[k], 32);                              \
    }

__global__ __launch_bounds__(256, 8) void lgcn_spmm_bf16(
    const int2* __restrict__ row_se,
    const int2* __restrict__ csr_cv,
    const uint4* __restrict__ xb,
    uint4* __restrict__ yb) {
    SPMM_BODY
    if (sub == 0) {
        uint4 p;
        p.x = f2bf(a[0]) | (f2bf(a[1]) << 16);
        p.y = f2bf(a[2]) | (f2bf(a[3]) << 16);
        p.z = f2bf(a[4]) | (f2bf(a[5]) << 16);
        p.w = f2bf(a[6]) | (f2bf(a[7]) << 16);
        yb[r * 8 + c] = p;
    }
}

// ---------------------------------------------------------------------------
// layer-3 SpMM: epilogue forms the final output directly:
// out = (x0 + y1 + y2 + y3) / 4,  x0 read straight from the fp32 inputs,
// y1/y2 re-read as bf16 (coalesced rows). No acc stream anywhere.
// ---------------------------------------------------------------------------
__global__ __launch_bounds__(256, 8) void lgcn_spmm_final(
    const int2* __restrict__ row_se,
    const int2* __restrict__ csr_cv,
    const uint4* __restrict__ xb,     // y2 bf16 (gather input)
    const uint4* __restrict__ y1b,
    const float4* __restrict__ user,
    const float4* __restrict__ item,
    float4* __restrict__ out) {
    SPMM_BODY
    if (sub == 0) {
        const float4* src = (r < USER_NUM) ? (user + (size_t)r * 16)
                                           : (item + (size_t)(r - USER_NUM) * 16);
        float4 f0 = src[c * 2];
        float4 f1 = src[c * 2 + 1];
        uint4 q1 = y1b[r * 8 + c];
        uint4 q2 = xb[r * 8 + c];    // y2 row (own row, coalesced)
        float4 o0, o1;
        o0.x = (f0.x + bflo(q1.x) + bflo(q2.x) + a[0]) * 0.25f;
        o0.y = (f0.y + bfhi(q1.x) + bfhi(q2.x) + a[1]) * 0.25f;
        o0.z = (f0.z + bflo(q1.y) + bflo(q2.y) + a[2]) * 0.25f;
        o0.w = (f0.w + bfhi(q1.y) + bfhi(q2.y) + a[3]) * 0.25f;
        o1.x = (f1.x + bflo(q1.z) + bflo(q2.z) + a[4]) * 0.25f;
        o1.y = (f1.y + bfhi(q1.z) + bfhi(q2.z) + a[5]) * 0.25f;
        o1.z = (f1.z + bflo(q1.w) + bflo(q2.w) + a[6]) * 0.25f;
        o1.w = (f1.w + bfhi(q1.w) + bfhi(q2.w) + a[7]) * 0.25f;
        int idx = r * 16 + c * 2;
        out[idx] = o0;
        out[idx + 1] = o1;
    }
}

extern "C" void kernel_launch(void* const* d_in, const int* in_sizes, int n_in,
                              void* d_out, int out_size, void* d_ws, size_t ws_size,
                              hipStream_t stream) {
    const float* user_emb = (const float*)d_in[0];
    const float* item_emb = (const float*)d_in[1];
    const int*   adj_row  = (const int*)d_in[2];
    const int*   adj_col  = (const int*)d_in[3];
    const float* adj_vals = (const float*)d_in[4];
    float* out = (float*)d_out;

    // workspace layout (~98.8 MB, unchanged footprint):
    //   xb_a (19.2MB) | csr_cv (38.4MB) | S (union): t_cv staging (40MB)
    //   during CSR build; y1b (19.2MB) + y2b (19.2MB) during layers | row_se
    char* base = (char*)d_ws;
    uint4* xb_a   = (uint4*)base;                               // 19.2 MB
    int2*  csr_cv = (int2*)(base + 19200000);                   // 38.4 MB
    char*  S      = base + 57600000;
    const size_t T_ENTRIES = (size_t)NCB * CB_CAP;              // 4,998,000
    int2*  t_cv   = (int2*)S;                                   // 40.0 MB
    uint4* y1b    = (uint4*)S;                                  // aliases t_cv
    uint4* y2b    = (uint4*)(S + 19200000);                     // aliases t_cv
    char*  tail   = S + T_ENTRIES * 8;
    int2*  row_se = (int2*)tail;                                // 1.2 MB
    int*   bucket_cursor = (int*)(tail + (size_t)N_NODES * 8);  // 147 ints

    // init: xb_a = bf16(concat(user,item))
    {
        int threads = 256;
        int blocks = (N_NODES * 8 + threads - 1) / threads;
        lgcn_init<<<blocks, threads, 0, stream>>>(
            (const float4*)user_emb, (const float4*)item_emb, xb_a);
    }

    // ---- CSR build: partition -> single fused finalize (1024 thr) ----
    lgcn_bcur_init<<<1, 256, 0, stream>>>(bucket_cursor);
    lgcn_partition<<<NTILES, 256, 0, stream>>>(
        adj_row, adj_col, adj_vals, bucket_cursor, t_cv);
    lgcn_finalize<<<NCB, 1024, 0, stream>>>(
        bucket_cursor, t_cv, csr_cv, row_se);

    // ---- 3 propagation layers ----
    const int spmm_block = 256;                       // 4 waves = 4 rows / block
    const int spmm_grid = (N_NODES * 64 + spmm_block - 1) / spmm_block;
    // layer 1: x0b -> y1b ; layer 2: y1b -> y2b ; layer 3: fused output
    lgcn_spmm_bf16<<<spmm_grid, spmm_block, 0, stream>>>(
        row_se, csr_cv, xb_a, y1b);
    lgcn_spmm_bf16<<<spmm_grid, spmm_block, 0, stream>>>(
        row_se, csr_cv, y1b, y2b);
    lgcn_spmm_final<<<spmm_grid, spmm_block, 0, stream>>>(
        row_se, csr_cv, y2b, y1b,
        (const float4*)user_emb, (const float4*)item_emb, (float4*)out);
}